// Round 1
// 425.130 us; speedup vs baseline: 1.1031x; 1.1031x over previous
//
#include <hip/hip_runtime.h>
#include <math.h>

#define NBR 4
#define NLAY 3
#define Bk 4
#define Tk 1024
#define DIN 32
#define DMODEL 128
#define DINNER 256
#define DSTATE 16
#define DTRANK 8
#define EMBEDk 64
#define BT (Bk*Tk)          /* 4096 rows per branch */
#define EPSF 1e-7f
#define MAXNF 10.0f
#define LCH 64              /* scan chunk length */
#define NCH (Tk/LCH)        /* 16 chunks */
#define UF 8                /* t-loop batch (latency amortization) */
#define NWB 320             /* dt|bc panel rows: 256 dt + 32 bc + 32 pad */

typedef __bf16 bf16x8 __attribute__((ext_vector_type(8)));
typedef float  f32x4  __attribute__((ext_vector_type(4)));
typedef unsigned short u16x8 __attribute__((ext_vector_type(8)));

__device__ __forceinline__ float siluf(float x){ return x / (1.f + __expf(-x)); }
__device__ __forceinline__ float softplusf(float x){ return (x > 20.f) ? x : log1pf(__expf(x)); }
__device__ __forceinline__ unsigned short f2b(float x){
    union { float f; unsigned u; } v; v.f = x;
    unsigned r = v.u + 0x7FFF + ((v.u >> 16) & 1);
    return (unsigned short)(r >> 16);
}
__device__ __forceinline__ float b2f(unsigned short u){
    union { unsigned u; float f; } v; v.u = ((unsigned)u) << 16; return v.f;
}

// async global->LDS, 16 B per lane; LDS dest = wave-uniform base + lane*16
__device__ __forceinline__ void gll16(const void* g, void* l){
    __builtin_amdgcn_global_load_lds(
        (const __attribute__((address_space(1))) unsigned int*)g,
        (__attribute__((address_space(3))) unsigned int*)l,
        16, 0, 0);
}

// dA[s] = q^(s+1) from q (A_s = -(s+1) fast path)
__device__ __forceinline__ void dA_pow(float q, float* dA){
    dA[0] = q;             dA[1] = q * q;
    dA[2] = dA[1] * dA[0]; dA[3] = dA[1] * dA[1];
    dA[4] = dA[3] * dA[0]; dA[5] = dA[3] * dA[1];
    dA[6] = dA[3] * dA[2]; dA[7] = dA[3] * dA[3];
    #pragma unroll
    for (int s = 8; s < 16; ++s) dA[s] = dA[s - 8] * dA[7];
}
__device__ __forceinline__ void dA_exp(float dtv, const float* Aa, float* dA){
    #pragma unroll
    for (int s = 0; s < 16; ++s) dA[s] = __expf(dtv * Aa[s]);
}

// ---------------------------------------------------------------------------
// bf16 MFMA GEMM: C = A(MxK) @ B(KxN).  A bf16 [M][K]; B TRANSPOSED bf16
// [N][K] (k contiguous).  64x64 tile, 4 waves (32x32 quadrants, 2x2x2
// mfma_f32_16x16x32_bf16), Kc=64.  LDS [kch][row][8]: fragment = 1
// ds_read_b128 at lane*16B.  Staging via global_load_lds (dest is exactly
// wave-uniform-base + lane*16 in this layout).
// MODE 0 (xz):  col<256 -> Cb bf16 (xp); col>=256 -> C1 fp32 silu (z)
// MODE 3 (dtbc): col<256 -> C0 softplus(v+bias) (dt fp32 ld 256);
//                col 256..287 -> C1 fp32 (bc ld 32); col>=288 dropped
// ---------------------------------------------------------------------------
template<int MODE>
__global__ __launch_bounds__(256) void bgemm_k(
    const unsigned short* __restrict__ Ab, long aBr, int K,
    const unsigned short* __restrict__ Bt, long bBr,
    float* __restrict__ C0, long c0Br,
    float* __restrict__ C1, long c1Br,
    unsigned short* __restrict__ Cb, long cbBr,
    const float* __restrict__ bias, long biasBr)
{
    const int br = blockIdx.z;
    Ab += (long)br * aBr;
    Bt += (long)br * bBr;
    if (MODE == 3) C0 += (long)br * c0Br;
    if (MODE == 0 || MODE == 3) C1 += (long)br * c1Br;
    if (MODE == 0) Cb += (long)br * cbBr;
    if (MODE == 3) bias += (long)br * biasBr;
    const int m0 = blockIdx.x * 64, n0 = blockIdx.y * 64;
    __shared__ __align__(16) unsigned short As[8 * 64 * 8];  // [kch][m][8]
    __shared__ __align__(16) unsigned short Bs[8 * 64 * 8];  // [kch][n][8]
    const int tid = threadIdx.x;
    const int lane = tid & 63, w = tid >> 6;
    const int wm = w >> 1, wn = w & 1;
    const int quad = lane >> 4, l15 = lane & 15;
    f32x4 acc00 = {0,0,0,0}, acc01 = {0,0,0,0}, acc10 = {0,0,0,0}, acc11 = {0,0,0,0};
    for (int kc = 0; kc < K; kc += 64) {
        #pragma unroll
        for (int it = 0; it < 2; ++it) {
            const int kch = w + it * 4;   // wave-uniform
            gll16(Ab + (long)(m0 + lane) * K + kc + kch * 8, &As[(kch * 64) * 8]);
            gll16(Bt + (long)(n0 + lane) * K + kc + kch * 8, &Bs[(kch * 64) * 8]);
        }
        __syncthreads();
        #pragma unroll
        for (int k0 = 0; k0 < 64; k0 += 32) {
            const int kch = (k0 >> 3) + quad;
            bf16x8 a0 = *(const bf16x8*)&As[(kch * 64 + wm * 32 +      l15) * 8];
            bf16x8 a1 = *(const bf16x8*)&As[(kch * 64 + wm * 32 + 16 + l15) * 8];
            bf16x8 b0 = *(const bf16x8*)&Bs[(kch * 64 + wn * 32 +      l15) * 8];
            bf16x8 b1 = *(const bf16x8*)&Bs[(kch * 64 + wn * 32 + 16 + l15) * 8];
            acc00 = __builtin_amdgcn_mfma_f32_16x16x32_bf16(a0, b0, acc00, 0, 0, 0);
            acc01 = __builtin_amdgcn_mfma_f32_16x16x32_bf16(a0, b1, acc01, 0, 0, 0);
            acc10 = __builtin_amdgcn_mfma_f32_16x16x32_bf16(a1, b0, acc10, 0, 0, 0);
            acc11 = __builtin_amdgcn_mfma_f32_16x16x32_bf16(a1, b1, acc11, 0, 0, 0);
        }
        __syncthreads();
    }
    #pragma unroll
    for (int e = 0; e < 4; ++e) {
        f32x4 a = (e == 0) ? acc00 : (e == 1) ? acc01 : (e == 2) ? acc10 : acc11;
        const int msub = (e >> 1) * 16, nsub = (e & 1) * 16;
        const int col = n0 + wn * 32 + nsub + l15;
        #pragma unroll
        for (int r = 0; r < 4; ++r) {
            const int row = m0 + wm * 32 + msub + quad * 4 + r;
            const float v = a[r];
            if (MODE == 0) {
                if (n0 < 256) Cb[(long)row * 256 + col] = f2b(v);
                else          C1[(long)row * 256 + (col - 256)] = siluf(v);
            } else {
                if (col < 256)      C0[(long)row * 256 + col] = softplusf(v + bias[col]);
                else if (col < 288) C1[(long)row * 32 + (col - 256)] = v;
            }
        }
    }
}

// ---------------------------------------------------------------------------
// Transpose + cvt: o_bf16[n][k] = W_f32[k][n].  64x64 tiles via LDS.
// ---------------------------------------------------------------------------
__global__ __launch_bounds__(256) void prepT_k(
    const float* __restrict__ W, unsigned short* __restrict__ o,
    int Kd, int Nd, long wBr, long oBr)
{
    const int br = blockIdx.z;
    W += (long)br * wBr; o += (long)br * oBr;
    const int n0 = blockIdx.x * 64, k0 = blockIdx.y * 64;
    __shared__ float tile[64][65];
    const int t = threadIdx.x;
    #pragma unroll
    for (int i = 0; i < 16; ++i) {
        int idx = t + i * 256;
        int kl = idx >> 6, nl = idx & 63;
        tile[kl][nl] = W[(long)(k0 + kl) * Nd + n0 + nl];
    }
    __syncthreads();
    #pragma unroll
    for (int i = 0; i < 16; ++i) {
        int idx = t + i * 256;
        int nl = idx >> 6, kl = idx & 63;
        o[(long)(n0 + nl) * Kd + k0 + kl] = f2b(tile[kl][nl]);
    }
}

// ---------------------------------------------------------------------------
// fp32 weight-product GEMM (once, at start): Wtmp[p][br] = Wout_p @ Win_{p+1}
// M=256, K=128, N=512; z = p*4+br.  64x64 tile, 4x4/thread.
// ---------------------------------------------------------------------------
__global__ __launch_bounds__(256) void sgemmW_k(
    const float* __restrict__ Wout, const float* __restrict__ Win,
    float* __restrict__ Wtmp)
{
    const int z = blockIdx.z, p = z >> 2, br = z & 3;
    const float* A  = Wout + (long)(br * NLAY + p) * DINNER * DMODEL;       // [256][128]
    const float* Bw = Win  + (long)(br * NLAY + p + 1) * DMODEL * 512;      // [128][512]
    float* C = Wtmp + (long)z * DINNER * 512;                               // [256][512]
    const int m0 = blockIdx.x * 64, n0 = blockIdx.y * 64;
    __shared__ float As[32][68];
    __shared__ float Bs[32][68];
    const int tid = threadIdx.x;
    const int tx = tid & 15, ty = tid >> 4;
    float acc[4][4] = {};
    for (int kc = 0; kc < DMODEL; kc += 32) {
        #pragma unroll
        for (int it = 0; it < 2; ++it) {
            int id = tid + it * 256;
            int r = id >> 3, c4 = (id & 7) << 2;
            float4 v = *(const float4*)(A + (long)(m0 + r) * DMODEL + kc + c4);
            As[c4+0][r] = v.x; As[c4+1][r] = v.y; As[c4+2][r] = v.z; As[c4+3][r] = v.w;
            int rb = id >> 4, cb = (id & 15) << 2;
            *(float4*)&Bs[rb][cb] = *(const float4*)(Bw + (long)(kc + rb) * 512 + n0 + cb);
        }
        __syncthreads();
        #pragma unroll
        for (int kk = 0; kk < 32; ++kk) {
            float4 a4 = *(const float4*)&As[kk][ty << 2];
            float4 b4 = *(const float4*)&Bs[kk][tx << 2];
            float av[4] = {a4.x, a4.y, a4.z, a4.w};
            float bv[4] = {b4.x, b4.y, b4.z, b4.w};
            #pragma unroll
            for (int i = 0; i < 4; ++i)
                #pragma unroll
                for (int j = 0; j < 4; ++j)
                    acc[i][j] = fmaf(av[i], bv[j], acc[i][j]);
        }
        __syncthreads();
    }
    #pragma unroll
    for (int i = 0; i < 4; ++i) {
        int row = m0 + (ty << 2) + i, col = n0 + (tx << 2);
        float4 v4; v4.x = acc[i][0]; v4.y = acc[i][1]; v4.z = acc[i][2]; v4.w = acc[i][3];
        *(float4*)(C + (long)row * 512 + col) = v4;
    }
}

// ---------------------------------------------------------------------------
// Build wcombT bf16 for ALL (br,l): o[bl][n][k];  bl = blockIdx.y (12).
// ---------------------------------------------------------------------------
__global__ __launch_bounds__(256) void prepC_k(
    const float* __restrict__ Wx, const float* __restrict__ Wdt,
    unsigned short* __restrict__ o)
{
    const int n = blockIdx.x, bl = blockIdx.y;
    const int k = threadIdx.x;
    const float* WxP = Wx + (long)bl * DINNER * 40;
    float v;
    if (n < 256) {
        const float* WdtP = Wdt + (long)bl * DTRANK * DINNER;
        float s = 0.f;
        #pragma unroll
        for (int r = 0; r < 8; ++r) s = fmaf(WxP[k * 40 + r], WdtP[r * DINNER + n], s);
        v = s;
    } else if (n < 288) {
        v = WxP[k * 40 + 8 + (n - 256)];
    } else {
        v = 0.f;
    }
    o[(long)bl * NWB * DINNER + (long)n * DINNER + k] = f2b(v);
}

// ---------------------------------------------------------------------------
// fp32 input projection (K=32): h_bf = bf16(x @ W_ip + b_ip).
// ---------------------------------------------------------------------------
__global__ __launch_bounds__(256) void proj_k(
    const float* __restrict__ A0, const float* __restrict__ A1,
    const float* __restrict__ A2, const float* __restrict__ A3,
    const float* __restrict__ Bw, const float* __restrict__ bias,
    unsigned short* __restrict__ Cb)
{
    const int br = blockIdx.z;
    const float* A = (br == 1) ? A1 : (br == 2) ? A2 : (br == 3) ? A3 : A0;
    Bw   += (long)br * DIN * DMODEL;
    bias += (long)br * DMODEL;
    Cb   += (long)br * BT * DMODEL;
    const int m0 = blockIdx.x * 64, n0 = blockIdx.y * 64;
    __shared__ float As[32][68];
    __shared__ float Bs[32][68];
    const int tid = threadIdx.x;
    const int tx = tid & 15, ty = tid >> 4;
    float acc[4][4] = {};
    {
        #pragma unroll
        for (int it = 0; it < 2; ++it) {
            int id = tid + it * 256;
            int r = id >> 3, c4 = (id & 7) << 2;
            float4 v = *(const float4*)(A + (long)(m0 + r) * DIN + c4);
            As[c4+0][r] = v.x; As[c4+1][r] = v.y; As[c4+2][r] = v.z; As[c4+3][r] = v.w;
            int rb = id >> 4, cb = (id & 15) << 2;
            *(float4*)&Bs[rb][cb] = *(const float4*)(Bw + (long)rb * DMODEL + n0 + cb);
        }
        __syncthreads();
        #pragma unroll
        for (int kk = 0; kk < 32; ++kk) {
            float4 a4 = *(const float4*)&As[kk][ty << 2];
            float4 b4 = *(const float4*)&Bs[kk][tx << 2];
            float av[4] = {a4.x, a4.y, a4.z, a4.w};
            float bv[4] = {b4.x, b4.y, b4.z, b4.w};
            #pragma unroll
            for (int i = 0; i < 4; ++i)
                #pragma unroll
                for (int j = 0; j < 4; ++j)
                    acc[i][j] = fmaf(av[i], bv[j], acc[i][j]);
        }
    }
    const int col = n0 + (tx << 2);
    float bs[4];
    #pragma unroll
    for (int j = 0; j < 4; ++j) bs[j] = bias[col + j];
    #pragma unroll
    for (int i = 0; i < 4; ++i) {
        const int row = m0 + (ty << 2) + i;
        #pragma unroll
        for (int j = 0; j < 4; ++j)
            Cb[(long)row * DMODEL + col + j] = f2b(acc[i][j] + bs[j]);
    }
}

// ---------------------------------------------------------------------------
// Depthwise causal conv (4 taps) + bias + silu: bf16 in -> bf16 out.
// Vectorized: 8 channels / thread, u16x8 (16 B) loads.
// ---------------------------------------------------------------------------
__global__ __launch_bounds__(256) void conv_k(
    const unsigned short* __restrict__ xp, const float* __restrict__ cw,
    const float* __restrict__ cb, unsigned short* __restrict__ xcb, int layer)
{
    const int br = blockIdx.y;
    const long base = (long)br * BT * DINNER;
    const long idx8 = ((long)blockIdx.x * 256 + threadIdx.x) * 8;
    const int d0 = (int)(idx8 & (DINNER - 1));      // multiple of 8
    const long row = idx8 >> 8;                     // row within branch
    const int t = (int)(row & (Tk - 1));
    const float* cwp = cw + ((long)(br * NLAY + layer) * DINNER + d0) * 4;  // [8][4]
    const float* cbp = cb + (long)(br * NLAY + layer) * DINNER + d0;
    u16x8 in[4];
    #pragma unroll
    for (int k = 0; k < 4; ++k) {
        const int tt = t + k - 3;
        if (tt >= 0) {
            in[k] = *(const u16x8*)(xp + base + idx8 + (long)(k - 3) * DINNER);
        } else {
            #pragma unroll
            for (int j = 0; j < 8; ++j) in[k][j] = 0;
        }
    }
    u16x8 o;
    #pragma unroll
    for (int j = 0; j < 8; ++j) {
        float acc = cbp[j];
        #pragma unroll
        for (int k = 0; k < 4; ++k)
            acc = fmaf(b2f(in[k][j]), cwp[j * 4 + k], acc);
        o[j] = f2b(siluf(acc));
    }
    *(u16x8*)(xcb + base + idx8) = o;
}

// ---------------------------------------------------------------------------
// Scan pass 1: per-chunk local recurrence from h=0 -> record (h_end[16], sumdt).
// ---------------------------------------------------------------------------
__global__ __launch_bounds__(256) void scan1_k(
    const float* __restrict__ dtb, const unsigned short* __restrict__ xcb,
    const float* __restrict__ bcb, const float* __restrict__ Alog,
    float* __restrict__ recbuf, int layer)
{
    const int c = blockIdx.x, b = blockIdx.y, br = blockIdx.z;
    const int d = threadIdx.x;
    const float* Ap = Alog + ((long)(br * NLAY + layer) * DINNER + d) * DSTATE;
    float Aa[16];
    bool pw = true;
    #pragma unroll
    for (int s = 0; s < 16; ++s) {
        Aa[s] = -__expf(Ap[s]);
        pw = pw && (fabsf(Aa[s] + (float)(s + 1)) < 1e-3f);
    }
    const long rbase = (long)br * BT + (long)b * Tk + (long)c * LCH;
    const float* dtp = dtb + rbase * DINNER + d;
    const unsigned short* xcp = xcb + rbase * DINNER + d;
    __shared__ float bcs[LCH * 32];
    {
        const float4* g = (const float4*)(bcb + rbase * 32);
        float4* l = (float4*)bcs;
        l[d] = g[d]; l[d + 256] = g[d + 256];
    }
    float dtc[UF], xcc[UF];
    #pragma unroll
    for (int u = 0; u < UF; ++u) {
        dtc[u] = dtp[(long)u * DINNER];
        xcc[u] = b2f(xcp[(long)u * DINNER]);
    }
    __syncthreads();
    float h[16];
    #pragma unroll
    for (int s = 0; s < 16; ++s) h[s] = 0.f;
    float sumdt = 0.f;
    for (int base = 0; base < LCH; base += UF) {
        const int nb = (base + UF < LCH) ? base + UF : base;
        float dtn[UF], xcn[UF];
        #pragma unroll
        for (int u = 0; u < UF; ++u) {
            dtn[u] = dtp[(long)(nb + u) * DINNER];
            xcn[u] = b2f(xcp[(long)(nb + u) * DINNER]);
        }
        #pragma unroll
        for (int u = 0; u < UF; ++u) {
            const int t = base + u;
            const float dtv = dtc[u];
            const float dtxc = dtv * xcc[u];
            sumdt += dtv;
            float dA[16];
            if (pw) dA_pow(__expf(-dtv), dA);
            else    dA_exp(dtv, Aa, dA);
            const float* bcT = bcs + t * 32;
            #pragma unroll
            for (int s = 0; s < 16; ++s)
                h[s] = fmaf(dA[s], h[s], dtxc * bcT[s]);
        }
        #pragma unroll
        for (int u = 0; u < UF; ++u) { dtc[u] = dtn[u]; xcc[u] = xcn[u]; }
    }
    float* sb = recbuf + (((long)(br * 4 + b) * (NCH - 1) + c) * 17) * 256 + d;
    #pragma unroll
    for (int s = 0; s < 16; ++s) sb[s * 256] = h[s];
    sb[16 * 256] = sumdt;
}

// ---------------------------------------------------------------------------
// Scan pass 3: fold preceding records into carry (software-pipelined), then
// local recurrence; yz = (y + Dp*xc)*silu(z) -> bf16.
// ---------------------------------------------------------------------------
__global__ __launch_bounds__(256) void scan3_k(
    const float* __restrict__ dtb, const unsigned short* __restrict__ xcb,
    const float* __restrict__ bcb, const float* __restrict__ zb,
    const float* __restrict__ Alog, const float* __restrict__ Dpar,
    const float* __restrict__ recbuf, unsigned short* __restrict__ yzb, int layer)
{
    const int c = blockIdx.x, b = blockIdx.y, br = blockIdx.z;
    const int d = threadIdx.x;
    const float* Ap = Alog + ((long)(br * NLAY + layer) * DINNER + d) * DSTATE;
    float Aa[16];
    bool pw = true;
    #pragma unroll
    for (int s = 0; s < 16; ++s) {
        Aa[s] = -__expf(Ap[s]);
        pw = pw && (fabsf(Aa[s] + (float)(s + 1)) < 1e-3f);
    }
    float h[16];
    #pragma unroll
    for (int s = 0; s < 16; ++s) h[s] = 0.f;
    if (c > 0) {
        const float* recB = recbuf + ((long)(br * 4 + b) * (NCH - 1)) * 17 * 256 + d;
        float rh[16], rs;
        #pragma unroll
        for (int s = 0; s < 16; ++s) rh[s] = recB[s * 256];
        rs = recB[16 * 256];
        for (int cc = 0; cc < c; ++cc) {
            float nh[16], ns = 0.f;
            if (cc + 1 < c) {
                const float* r2 = recB + (long)(cc + 1) * 17 * 256;
                #pragma unroll
                for (int s = 0; s < 16; ++s) nh[s] = r2[s * 256];
                ns = r2[16 * 256];
            } else {
                #pragma unroll
                for (int s = 0; s < 16; ++s) nh[s] = 0.f;
            }
            float P[16];
            if (pw) dA_pow(__expf(-rs), P);
            else    dA_exp(rs, Aa, P);
            #pragma unroll
            for (int s = 0; s < 16; ++s) h[s] = fmaf(h[s], P[s], rh[s]);
            #pragma unroll
            for (int s = 0; s < 16; ++s) rh[s] = nh[s];
            rs = ns;
        }
    }
    const float Dp = Dpar[(br * NLAY + layer) * DINNER + d];
    const long rbase = (long)br * BT + (long)b * Tk + (long)c * LCH;
    const float* dtp = dtb + rbase * DINNER + d;
    const unsigned short* xcp = xcb + rbase * DINNER + d;
    const float* zp  = zb  + rbase * DINNER + d;
    unsigned short* yp = yzb + rbase * DINNER + d;
    __shared__ float bcs[LCH * 32];
    {
        const float4* g = (const float4*)(bcb + rbase * 32);
        float4* l = (float4*)bcs;
        l[d] = g[d]; l[d + 256] = g[d + 256];
    }
    float dtc[UF], xcc[UF], zc[UF];
    #pragma unroll
    for (int u = 0; u < UF; ++u) {
        dtc[u] = dtp[(long)u * DINNER];
        xcc[u] = b2f(xcp[(long)u * DINNER]);
        zc[u]  = zp[(long)u * DINNER];
    }
    __syncthreads();
    for (int base = 0; base < LCH; base += UF) {
        const int nb = (base + UF < LCH) ? base + UF : base;
        float dtn[UF], xcn[UF], zn[UF];
        #pragma unroll
        for (int u = 0; u < UF; ++u) {
            dtn[u] = dtp[(long)(nb + u) * DINNER];
            xcn[u] = b2f(xcp[(long)(nb + u) * DINNER]);
            zn[u]  = zp[(long)(nb + u) * DINNER];
        }
        #pragma unroll
        for (int u = 0; u < UF; ++u) {
            const int t = base + u;
            const float dtv = dtc[u], xcv = xcc[u];
            const float dtxc = dtv * xcv;
            float dA[16];
            if (pw) dA_pow(__expf(-dtv), dA);
            else    dA_exp(dtv, Aa, dA);
            const float* bcT = bcs + t * 32;
            #pragma unroll
            for (int s = 0; s < 16; ++s)
                h[s] = fmaf(dA[s], h[s], dtxc * bcT[s]);
            float y0 = 0.f, y1 = 0.f, y2 = 0.f, y3 = 0.f;
            #pragma unroll
            for (int s = 0; s < 16; s += 4) {
                y0 = fmaf(h[s+0], bcT[16+s+0], y0);
                y1 = fmaf(h[s+1], bcT[16+s+1], y1);
                y2 = fmaf(h[s+2], bcT[16+s+2], y2);
                y3 = fmaf(h[s+3], bcT[16+s+3], y3);
            }
            const float y = (y0 + y1) + (y2 + y3) + Dp * xcv;
            yp[(long)t * DINNER] = f2b(y * zc[u]);
        }
        #pragma unroll
        for (int u = 0; u < UF; ++u) { dtc[u] = dtn[u]; xcc[u] = xcn[u]; zc[u] = zn[u]; }
    }
}

// ---------------------------------------------------------------------------
// Column-sum stage 1: part[brb][ch][256] = sum over 128 rows of yz (bf16).
// mean_t(yz @ Wout2) == mean_t(yz) @ Wout2  (linearity) -> no h GEMM needed.
// ---------------------------------------------------------------------------
__global__ __launch_bounds__(256) void csum1_k(
    const unsigned short* __restrict__ yz, float* __restrict__ part)
{
    const int ch = blockIdx.x, brb = blockIdx.y;
    const int br = brb >> 2, b = brb & 3;
    const long rbase = (long)br * BT + (long)b * Tk + (long)ch * 128;
    const int tid = threadIdx.x;
    const int cg = tid & 31;        // col group (8 cols)
    const int ro = tid >> 5;        // row offset 0..7
    const unsigned short* p = yz + (rbase + ro) * DINNER + cg * 8;
    float acc[8] = {0,0,0,0,0,0,0,0};
    for (int it = 0; it < 16; ++it) {
        u16x8 v = *(const u16x8*)(p + (long)it * 8 * DINNER);
        #pragma unroll
        for (int j = 0; j < 8; ++j) acc[j] += b2f(v[j]);
    }
    __shared__ float sm[8][256];
    #pragma unroll
    for (int j = 0; j < 8; ++j) sm[ro][cg * 8 + j] = acc[j];
    __syncthreads();
    float s = 0.f;
    #pragma unroll
    for (int r = 0; r < 8; ++r) s += sm[r][tid];
    part[((long)brb * 8 + ch) * 256 + tid] = s;
}

// ---------------------------------------------------------------------------
// Column-sum stage 2 + projection: z_t = (mean yz) @ Wout2 @ Wop + bop.
// ---------------------------------------------------------------------------
__global__ __launch_bounds__(256) void csum2_k(
    const float* __restrict__ part, const float* __restrict__ Wout,
    const float* __restrict__ Wop, const float* __restrict__ bop,
    float* __restrict__ outzt)
{
    const int brb = blockIdx.x;
    const int br = brb >> 2, b = brb & 3;
    const int tid = threadIdx.x;
    __shared__ float v[256];
    __shared__ float u[128];
    float s = 0.f;
    #pragma unroll
    for (int ch = 0; ch < 8; ++ch) s += part[((long)brb * 8 + ch) * 256 + tid];
    v[tid] = s * (1.0f / Tk);
    __syncthreads();
    if (tid < 128) {
        const float* W2 = Wout + (long)(br * NLAY + 2) * DINNER * DMODEL;  // [256][128]
        float a = 0.f;
        for (int k = 0; k < 256; ++k) a = fmaf(v[k], W2[k * DMODEL + tid], a);
        u[tid] = a;
    }
    __syncthreads();
    if (tid < EMBEDk) {
        float a = bop[br * EMBEDk + tid];
        for (int k = 0; k < 128; ++k)
            a = fmaf(u[k], Wop[(long)br * DMODEL * EMBEDk + k * EMBEDk + tid], a);
        outzt[br * (Bk * EMBEDk) + b * EMBEDk + tid] = a;
    }
}

// ---------------------------------------------------------------------------
// Lorentz epilogue.
// ---------------------------------------------------------------------------
__global__ __launch_bounds__(64) void final_k(
    const float* __restrict__ zt, float* __restrict__ out, const float* __restrict__ eff)
{
    const float es = tanhf(eff[0]);
    __shared__ float us[NBR][Bk][EMBEDk];
    const int t = threadIdx.x;
    if (t < 16) {
        const int br = t >> 2, b = t & 3;
        const float* z = zt + br * (Bk * EMBEDk) + b * EMBEDk;
        float n2 = 0.f;
        for (int e = 0; e < EMBEDk; ++e) { float v = z[e] * es; n2 = fmaf(v, v, n2); }
        const float n  = sqrtf(n2);
        const float nc = fminf(fmaxf(n, EPSF), MAXNF);
        const float sc = nc / fmaxf(n, EPSF);
        const float sh = sinhf(nc) / nc;
        const float fac = es * sc * sh;
        float* zh = out + 1024 + br * (Bk * (EMBEDk + 1)) + b * (EMBEDk + 1);
        float sp2 = 0.f;
        for (int e = 0; e < EMBEDk; ++e) {
            float spv = z[e] * fac;
            sp2 = fmaf(spv, spv, sp2);
            zh[1 + e] = spv;
            us[br][b][e] = spv;
        }
        const float t0 = sqrtf(1.f + sp2);
        zh[0] = t0;
        const float dd  = acoshf(fmaxf(t0, 1.f + EPSF));
        const float spn = fmaxf(sqrtf(sp2), EPSF);
        const float rr  = dd / spn;
        for (int e = 0; e < EMBEDk; ++e) us[br][b][e] *= rr;
    }
    __syncthreads();
    if (t < 4) {
        const int b = t;
        float ct[EMBEDk];
        float* cto = out + 2064 + b * EMBEDk;
        for (int e = 0; e < EMBEDk; ++e) {
            float v = us[0][b][e] + us[1][b][e] + us[2][b][e] + us[3][b][e];
            ct[e] = v; cto[e] = v;
        }
        float n2 = 0.f;
        for (int e = 0; e < EMBEDk; ++e) { float v = ct[e] * es; n2 = fmaf(v, v, n2); }
        const float n  = sqrtf(n2);
        const float nc = fminf(fmaxf(n, EPSF), MAXNF);
        const float sc = nc / fmaxf(n, EPSF);
        const float sh = sinhf(nc) / nc;
        const float fac = es * sc * sh;
        float* ch = out + 2320 + b * (EMBEDk + 1);
        float sp2 = 0.f;
        for (int e = 0; e < EMBEDk; ++e) {
            float spv = ct[e] * fac;
            sp2 = fmaf(spv, spv, sp2);
            ch[1 + e] = spv;
        }
        ch[0] = sqrtf(1.f + sp2);
    }
}

extern "C" void kernel_launch(void* const* d_in, const int* in_sizes, int n_in,
                              void* d_out, int out_size, void* d_ws, size_t ws_size,
                              hipStream_t stream)
{
    const float* X0 = (const float*)d_in[0];
    const float* X1 = (const float*)d_in[1];
    const float* X2 = (const float*)d_in[2];
    const float* X3 = (const float*)d_in[3];
    const float* W_ip   = (const float*)d_in[4];
    const float* b_ip   = (const float*)d_in[5];
    const float* W_in   = (const float*)d_in[6];
    const float* conv_w = (const float*)d_in[7];
    const float* conv_b = (const float*)d_in[8];
    const float* W_x    = (const float*)d_in[9];
    const float* W_dt   = (const float*)d_in[10];
    const float* b_dt   = (const float*)d_in[11];
    const float* A_log  = (const float*)d_in[12];
    const float* D_par  = (const float*)d_in[13];
    const float* W_out  = (const float*)d_in[14];
    const float* W_op   = (const float*)d_in[15];
    const float* b_op   = (const float*)d_in[16];
    const float* eff    = (const float*)d_in[17];
    float* out = (float*)d_out;
    float* ws  = (float*)d_ws;

    // ---- workspace (no aliasing) ----
    float* buf_z  = ws;                                   // 4.19M f32
    float* buf_dt = buf_z  + (long)NBR * BT * DINNER;     // 4.19M f32
    float* buf_bc = buf_dt + (long)NBR * BT * DINNER;     // 0.52M f32
    float* part   = buf_bc + (long)NBR * BT * 32;         // 16*8*256 f32 (csum partials)
    float* recbuf = part   + (long)NBR * BT * DMODEL;     // 1.04M f32
    float* Wtmp   = recbuf + (long)16 * (NCH - 1) * 17 * 256;  // 8*256*512 f32
    unsigned short* h_bf  = (unsigned short*)(Wtmp + (long)8 * DINNER * 512);
    unsigned short* xp_bf = h_bf  + (long)NBR * BT * DMODEL;   // 4.19M u16
    unsigned short* xc_bf = xp_bf + (long)NBR * BT * DINNER;   // 4.19M u16
    unsigned short* yz_bf = xc_bf + (long)NBR * BT * DINNER;   // 4.19M u16
    unsigned short* Win0T = yz_bf + (long)NBR * BT * DINNER;   // 4*512*128 u16
    unsigned short* WfT   = Win0T + (long)NBR * 512 * DMODEL;  // 8*512*256 u16
    unsigned short* WcT   = WfT   + (long)8 * 512 * DINNER;    // 12*320*256 u16

    // ---- weight prep (once) ----
    prepT_k<<<dim3(8, 2, NBR), 256, 0, stream>>>(
        W_in, Win0T, DMODEL, 512, (long)NLAY * DMODEL * 512, (long)512 * DMODEL);
    sgemmW_k<<<dim3(4, 8, 8), 256, 0, stream>>>(W_out, W_in, Wtmp);
    prepT_k<<<dim3(8, 4, 8), 256, 0, stream>>>(
        Wtmp, WfT, DINNER, 512, (long)DINNER * 512, (long)512 * DINNER);
    prepC_k<<<dim3(NWB, NBR * NLAY), 256, 0, stream>>>(W_x, W_dt, WcT);

    // ---- input projection: h_bf = bf16(x @ W_ip + b_ip) ----
    proj_k<<<dim3(BT / 64, DMODEL / 64, NBR), 256, 0, stream>>>(
        X0, X1, X2, X3, W_ip, b_ip, h_bf);

    for (int l = 0; l < NLAY; ++l) {
        // xz: l==0: h_bf @ Win_0 (K=128); else: yz_bf @ (Wout_{l-1}·Win_l) (K=256)
        if (l == 0) {
            bgemm_k<0><<<dim3(BT / 64, 8, NBR), 256, 0, stream>>>(
                h_bf, (long)BT * DMODEL, DMODEL,
                Win0T, (long)512 * DMODEL,
                nullptr, 0, buf_z, (long)BT * DINNER,
                xp_bf, (long)BT * DINNER, nullptr, 0);
        } else {
            bgemm_k<0><<<dim3(BT / 64, 8, NBR), 256, 0, stream>>>(
                yz_bf, (long)BT * DINNER, DINNER,
                WfT + (long)(l - 1) * 4 * 512 * DINNER, (long)512 * DINNER,
                nullptr, 0, buf_z, (long)BT * DINNER,
                xp_bf, (long)BT * DINNER, nullptr, 0);
        }
        // depthwise conv + silu (bf16 -> bf16), 8 channels/thread
        conv_k<<<dim3((BT * DINNER) / (256 * 8), NBR), 256, 0, stream>>>(
            xp_bf, conv_w, conv_b, xc_bf, l);
        // dt = softplus(xc @ wc + b_dt); bc = xc @ wcBC
        bgemm_k<3><<<dim3(BT / 64, NWB / 64, NBR), 256, 0, stream>>>(
            xc_bf, (long)BT * DINNER, DINNER,
            WcT + (long)l * NWB * DINNER, (long)NLAY * NWB * DINNER,
            buf_dt, (long)BT * DINNER, buf_bc, (long)BT * 32,
            nullptr, 0, b_dt + l * DINNER, (long)NLAY * DINNER);
        // chunked scan: records -> (fold + local + y) -> yz bf16
        scan1_k<<<dim3(NCH - 1, Bk, NBR), 256, 0, stream>>>(
            buf_dt, xc_bf, buf_bc, A_log, recbuf, l);
        scan3_k<<<dim3(NCH, Bk, NBR), 256, 0, stream>>>(
            buf_dt, xc_bf, buf_bc, buf_z, A_log, D_par, recbuf, yz_bf, l);
    }

    // z_t = mean_t(yz) @ Wout2 @ Wop + bop   (linearity of mean)
    csum1_k<<<dim3(8, 16), 256, 0, stream>>>(yz_bf, part);
    csum2_k<<<16, 256, 0, stream>>>(part, W_out, W_op, b_op, out);
    final_k<<<1, 64, 0, stream>>>(out, out, eff);
}